// Round 15
// baseline (216.721 us; speedup 1.0000x reference)
//
#include <hip/hip_runtime.h>
#include <stdint.h>

typedef unsigned short u16;
typedef __attribute__((ext_vector_type(8))) short bf16x8;   // 8 bf16 = 4 VGPRs
typedef __attribute__((ext_vector_type(4))) float f32x4;

#define BATCH   4
#define CH      256
#define NPIX    4096      // 64*64
#define NGROUPS 32
#define CPG     8
#define EPS     1e-5f

#define NSPLIT 4
#define SPLEN  (NPIX / NSPLIT)
#define ATK    32
#define NIT    (SPLEN / ATK)     // 32
#define WSTR   264        // weight LDS row stride
#define QTILES 4          // qkv: pixel-tiles per block (weight-stage amortization; R15: 2->4)

// ---------- bf16 helpers ----------
__device__ __forceinline__ float bf2f(u16 u) {
    union { uint32_t i; float f; } v; v.i = ((uint32_t)u) << 16; return v.f;
}
__device__ __forceinline__ u16 f2bf(float f) {
    union { float f; uint32_t i; } v; v.f = f;
    uint32_t x = v.i;
    uint32_t r = (x + 0x7fffu + ((x >> 16) & 1u)) >> 16;
    return (u16)r;
}
__device__ __forceinline__ void unpack2(uint32_t u, float& a, float& b) {
    union { uint32_t i; float f; } lo, hi;
    lo.i = u << 16; hi.i = u & 0xffff0000u;
    a = lo.f; b = hi.f;
}
__device__ __forceinline__ void unpack8(uint4 u, float* f) {
    unpack2(u.x, f[0], f[1]); unpack2(u.y, f[2], f[3]);
    unpack2(u.z, f[4], f[5]); unpack2(u.w, f[6], f[7]);
}

// ---------- runtime input-dtype detection (fp32 vs bf16 ambiguity) ----------
__device__ __forceinline__ bool detect_f32(const void* xv) {
    const u16* p = (const u16*)xv;
    int bad = 0;
    #pragma unroll
    for (int i = 0; i < 32; i++) {
        u16 v = p[2 * i];
        int e = (v >> 7) & 0xff;
        bad += (e < 0x68 || e > 0x90) ? 1 : 0;
    }
    return bad >= 10;
}
__device__ __forceinline__ float load1(const void* b, size_t i, bool f32) {
    return f32 ? ((const float*)b)[i] : bf2f(((const u16*)b)[i]);
}
__device__ __forceinline__ void store1(void* b, size_t i, bool f32, float v) {
    if (f32) ((float*)b)[i] = v; else ((u16*)b)[i] = f2bf(v);
}
__device__ __forceinline__ void load4v(const void* base, size_t off, bool f32, float* f) {
    if (f32) {
        float4 a = *(const float4*)((const float*)base + off);
        f[0] = a.x; f[1] = a.y; f[2] = a.z; f[3] = a.w;
    } else {
        uint2 u = *(const uint2*)((const u16*)base + off);
        unpack2(u.x, f[0], f[1]); unpack2(u.y, f[2], f[3]);
    }
}
__device__ __forceinline__ void load8v(const void* base, size_t off, bool f32, float* f) {
    if (f32) {
        const float4* p = (const float4*)((const float*)base + off);
        float4 a = p[0], b = p[1];
        f[0] = a.x; f[1] = a.y; f[2] = a.z; f[3] = a.w;
        f[4] = b.x; f[5] = b.y; f[6] = b.z; f[7] = b.w;
    } else {
        uint4 u = *(const uint4*)((const u16*)base + off);
        unpack8(u, f);
    }
}

// ---------- K0: weights -> bf16 ----------
__global__ __launch_bounds__(256) void wconv(const void* __restrict__ qkv_w,
                                             const void* __restrict__ proj_w,
                                             u16* __restrict__ wq, u16* __restrict__ wp) {
    bool f32q = detect_f32(qkv_w);
    bool f32p = detect_f32(proj_w);
    int i = blockIdx.x * 256 + threadIdx.x;
    for (int e = i; e < 768 * 256; e += 256 * 256)
        wq[e] = f2bf(load1(qkv_w, e, f32q));
    for (int e = i; e < 256 * 256; e += 256 * 256)
        wp[e] = f2bf(load1(proj_w, e, f32p));
}

// ---------- K1: GroupNorm stats ----------
__global__ __launch_bounds__(256) void gn_stats(const void* __restrict__ x,
                                                float* __restrict__ stats, int b0) {
    bool f32 = detect_f32(x);
    int bg = b0 * NGROUPS + blockIdx.x;
    int t  = threadIdx.x;
    size_t base = (size_t)bg * (CPG * NPIX);
    float s = 0.f, s2 = 0.f;
    for (int i = t * 8; i < CPG * NPIX; i += 256 * 8) {
        float f[8]; load8v(x, base + i, f32, f);
        #pragma unroll
        for (int e = 0; e < 8; e++) { s += f[e]; s2 += f[e] * f[e]; }
    }
    #pragma unroll
    for (int off = 1; off < 64; off <<= 1) {
        s  += __shfl_xor(s,  off);
        s2 += __shfl_xor(s2, off);
    }
    __shared__ float red[8];
    int w = t >> 6;
    if ((t & 63) == 0) { red[w * 2] = s; red[w * 2 + 1] = s2; }
    __syncthreads();
    if (t == 0) {
        float S  = red[0] + red[2] + red[4] + red[6];
        float S2 = red[1] + red[3] + red[5] + red[7];
        float n  = (float)(CPG * NPIX);
        float mu = S / n;
        float var = S2 / n - mu * mu;
        stats[bg * 2]     = mu;
        stats[bg * 2 + 1] = rsqrtf(var + EPS);
    }
}

// ---------- K2: GN-apply + transpose: x[c][n] -> xt[n][c] normalized bf16 ----------
__global__ __launch_bounds__(256) void xgn(const void* __restrict__ x,
                                           const void* __restrict__ gn_w,
                                           const void* __restrict__ gn_b,
                                           const float* __restrict__ stats,
                                           u16* __restrict__ xt, int b0) {
    bool f32 = detect_f32(x);
    __shared__ u16 T[64][72];
    int bl = blockIdx.z, bg = b0 + bl;
    int n0 = blockIdx.x * 64, c0 = blockIdx.y * 64;
    int t = threadIdx.x;
    int tc = t >> 4, tn = (t & 15) * 4;
    #pragma unroll
    for (int i = 0; i < 4; i++) {
        int cl = tc + i * 16;
        int c = c0 + cl;
        int g = c >> 3;
        float mu = stats[(bg * NGROUPS + g) * 2];
        float rs = stats[(bg * NGROUPS + g) * 2 + 1];
        float wv = load1(gn_w, c, f32) * rs;
        float bv = load1(gn_b, c, f32) - mu * wv;
        float a[4];
        load4v(x, ((size_t)(bg * CH + c)) * NPIX + n0 + tn, f32, a);
        #pragma unroll
        for (int j = 0; j < 4; j++) T[cl][tn + j] = f2bf(a[j] * wv + bv);
    }
    __syncthreads();
    #pragma unroll
    for (int i = 0; i < 2; i++) {
        int e = t + i * 256;
        int nl = e >> 3, cc = (e & 7) * 8;
        union { uint4 v; u16 s[8]; } pk;
        #pragma unroll
        for (int j = 0; j < 8; j++) pk.s[j] = T[cc + j][nl];
        *(uint4*)(xt + ((size_t)(bl * NPIX) + n0 + nl) * CH + c0 + cc) = pk.v;
    }
}

// ---------- K3: QKV GEMM (MFMA; weights in LDS, A direct-global contiguous) ----------
// V stored kv-permuted within 32-groups for the SWAPPED-QK attention:
//   phys kv j -> slot jj = ((j&12)<<1) | ((j>>4)<<2) | (j&3)
// QTILES=4 pixel-tiles per block amortize the 33KB weight stage 4x (R11: 2x was +4us).
__global__ __launch_bounds__(256, 3) void qkv_mfma(const u16* __restrict__ xt,
                                                   const u16* __restrict__ wq,
                                                   const void* __restrict__ qkv_b,
                                                   u16* __restrict__ qk,
                                                   u16* __restrict__ vt) {
    __shared__ u16 Ws[64 * WSTR];    // 33 KB
    __shared__ u16 T2b[128 * 72];    // 18 KB transpose scratch
    bool f32b = detect_f32(qkv_b);
    int bl = blockIdx.z;
    int o0 = blockIdx.y * 64;
    int t = threadIdx.x;
    int w = t >> 6, lane = t & 63;
    int l15 = lane & 15, quad = lane >> 4;

    #pragma unroll
    for (int i = 0; i < 8; i++) {
        int e = t + i * 256;
        *(uint4*)(Ws + (e >> 5) * WSTR + (e & 31) * 8) =
            *(const uint4*)(wq + (size_t)(o0 + (e >> 5)) * CH + (e & 31) * 8);
    }
    __syncthreads();

    bool isv = (o0 >= 512);
    for (int tt = 0; tt < QTILES; tt++) {
        int n0 = (blockIdx.x * QTILES + tt) * 128;
        int pbase = n0 + w * 32;
        const u16* xa = xt + ((size_t)(bl * NPIX + pbase)) * CH;

        f32x4 acc[2][4];
        #pragma unroll
        for (int m = 0; m < 2; m++)
            #pragma unroll
            for (int n = 0; n < 4; n++)
                #pragma unroll
                for (int r = 0; r < 4; r++) acc[m][n][r] = 0.f;

        #pragma unroll
        for (int kc = 0; kc < 8; kc++) {
            bf16x8 a0 = *(const bf16x8*)(xa + (size_t)(l15) * CH + kc * 32 + quad * 8);
            bf16x8 a1 = *(const bf16x8*)(xa + (size_t)(16 + l15) * CH + kc * 32 + quad * 8);
            #pragma unroll
            for (int n = 0; n < 4; n++) {
                bf16x8 b = *(const bf16x8*)(Ws + (n * 16 + l15) * WSTR + kc * 32 + quad * 8);
                acc[0][n] = __builtin_amdgcn_mfma_f32_16x16x32_bf16(a0, b, acc[0][n], 0, 0, 0);
                acc[1][n] = __builtin_amdgcn_mfma_f32_16x16x32_bf16(a1, b, acc[1][n], 0, 0, 0);
            }
        }

        if (!isv) {
            // ---- q/k: LDS transpose (T2b) + coalesced uint4 stores ----
            __syncthreads();          // prior tile's T2b reads complete
            #pragma unroll
            for (int n = 0; n < 4; n++) {
                int o = o0 + n * 16 + l15;
                float bias = load1(qkv_b, o, f32b);
                #pragma unroll
                for (int m = 0; m < 2; m++)
                    #pragma unroll
                    for (int r = 0; r < 4; r++) {
                        int prow = w * 32 + m * 16 + quad * 4 + r;
                        T2b[prow * 72 + n * 16 + l15] = f2bf(acc[m][n][r] + bias);
                    }
            }
            __syncthreads();
            #pragma unroll
            for (int i = 0; i < 4; i++) {
                int e = t + i * 256;  // 1024 entries = 128 pix x 8 chunks
                int p = e >> 3, c = (e & 7) * 8;
                uint4 v = *(const uint4*)(T2b + p * 72 + c);
                *(uint4*)(qk + ((size_t)(bl * NPIX + n0 + p)) * 512 + o0 + c) = v;
            }
        } else {
            // ---- v: packed uint2 stores (4 contiguous u16 per (n,m)) ----
            #pragma unroll
            for (int n = 0; n < 4; n++) {
                int o = o0 + n * 16 + l15;
                float bias = load1(qkv_b, o, f32b);
                size_t rowb = ((size_t)(bl * CH + o - 512)) * NPIX + pbase;
                #pragma unroll
                for (int m = 0; m < 2; m++) {
                    union { uint2 v; u16 s[4]; } pk;
                    #pragma unroll
                    for (int r = 0; r < 4; r++) pk.s[r] = f2bf(acc[m][n][r] + bias);
                    *(uint2*)(vt + rowb + quad * 8 + m * 4) = pk.v;
                }
            }
        }
    }
}

// ---------- K4: MFMA flash attention — R15: byte-exact R12 (verified best, 87.0us) ----------
// attn is latency-pinned: 6 schedule variants all land 87-90us; registers exactly
// full (4 spill confirmations); direct-global operands fatal (2 confirmations).
// R14's epilogue transpose was +2.5us — reverted to plain scattered stores.
__global__ __launch_bounds__(256, 2) void attn_mfma(const u16* __restrict__ qk,
                                                    const u16* __restrict__ vt,
                                                    u16* __restrict__ Opart,
                                                    float* __restrict__ lpart,
                                                    int NE, int NR) {
    __shared__ u16 Ks[2][ATK * 256];     // 2 x 16 KB, col-swizzled (col ^ (row&7))
    __shared__ u16 Vts[2][CH * 32];      // 2 x 16 KB, slot-swizzled (slot ^ (row&3))
    int bl    = blockIdx.z;
    int split = blockIdx.y;
    int q0    = blockIdx.x * 128;
    int t     = threadIdx.x;
    int w     = t >> 6, lane = t & 63;
    int l15   = lane & 15, quad = lane >> 4;

    const u16* qkb = qk + (size_t)bl * NPIX * 512;
    const u16* vtb = vt + (size_t)bl * CH * NPIX;
    int kvbase = split * SPLEN;

    // Q fragments (B-operand of swapped QK): lane l15 = q-col, k = quad*8+e
    bf16x8 qf[2][8];
    #pragma unroll
    for (int m = 0; m < 2; m++) {
        const u16* qrow = qkb + (size_t)(q0 + w * 32 + m * 16 + l15) * 512;
        #pragma unroll
        for (int kc = 0; kc < 8; kc++)
            qf[m][kc] = *(const bf16x8*)(qrow + kc * 32 + quad * 8);
    }
    f32x4 o[2][16];
    #pragma unroll
    for (int m = 0; m < 2; m++)
        #pragma unroll
        for (int i = 0; i < 16; i++)
            #pragma unroll
            for (int r = 0; r < 4; r++) o[m][i][r] = 0.f;
    float lsum[2] = {0.f, 0.f};
    const float scale = 0.0625f;
    int swz = l15 & 7;

    // ---- prologue: DMA tile 0 into buffer 0, drain ----
    #pragma unroll
    for (int i = 0; i < 4; i++) {
        int g = t + i * 256;
        int row = g >> 5, pcol = g & 31;
        int lcol = pcol ^ (row & 7);
        __builtin_amdgcn_global_load_lds(
            (const void*)(qkb + (size_t)(kvbase + row) * 512 + 256 + lcol * 8),
            (void*)(&Ks[0][0] + (size_t)g * 8), 16, 0, 0);
    }
    #pragma unroll
    for (int i = 0; i < 4; i++) {
        int g = t + i * 256;
        int row = g >> 2, s = g & 3;
        __builtin_amdgcn_global_load_lds(
            (const void*)(vtb + (size_t)row * NPIX + kvbase + (s ^ (row & 3)) * 8),
            (void*)(&Vts[0][0] + (size_t)g * 8), 16, 0, 0);
    }
    __syncthreads();

    for (int it = 0; it < NIT; it++) {
        int cur = it & 1;
        // issue tile t+1's DMA into the other buffer — latency hides under compute
        if (it + 1 < NIT) {
            int kv1 = kvbase + (it + 1) * ATK;
            u16* KsB = &Ks[cur ^ 1][0];
            u16* VsB = &Vts[cur ^ 1][0];
            #pragma unroll
            for (int i = 0; i < 4; i++) {
                int g = t + i * 256;
                int row = g >> 5, pcol = g & 31;
                int lcol = pcol ^ (row & 7);
                __builtin_amdgcn_global_load_lds(
                    (const void*)(qkb + (size_t)(kv1 + row) * 512 + 256 + lcol * 8),
                    (void*)(KsB + (size_t)g * 8), 16, 0, 0);
            }
            #pragma unroll
            for (int i = 0; i < 4; i++) {
                int g = t + i * 256;
                int row = g >> 2, s = g & 3;
                __builtin_amdgcn_global_load_lds(
                    (const void*)(vtb + (size_t)row * NPIX + kv1 + (s ^ (row & 3)) * 8),
                    (void*)(VsB + (size_t)g * 8), 16, 0, 0);
            }
        }
        const u16* KsC = &Ks[cur][0];
        const u16* VsC = &Vts[cur][0];

        // S^T = K.Q^T (K reads use the same XOR swizzle as the DMA source)
        f32x4 sT[2][2];
        #pragma unroll
        for (int kt = 0; kt < 2; kt++)
            #pragma unroll
            for (int qt = 0; qt < 2; qt++)
                #pragma unroll
                for (int r = 0; r < 4; r++) sT[kt][qt][r] = 0.f;
        #pragma unroll
        for (int kc = 0; kc < 8; kc++) {
            int sc = (kc * 4 + quad) ^ swz;
            bf16x8 a0 = *(const bf16x8*)(KsC + l15 * 256 + sc * 8);
            bf16x8 a1 = *(const bf16x8*)(KsC + (16 + l15) * 256 + sc * 8);
            sT[0][0] = __builtin_amdgcn_mfma_f32_16x16x32_bf16(a0, qf[0][kc], sT[0][0], 0, 0, 0);
            sT[0][1] = __builtin_amdgcn_mfma_f32_16x16x32_bf16(a0, qf[1][kc], sT[0][1], 0, 0, 0);
            sT[1][0] = __builtin_amdgcn_mfma_f32_16x16x32_bf16(a1, qf[0][kc], sT[1][0], 0, 0, 0);
            sT[1][1] = __builtin_amdgcn_mfma_f32_16x16x32_bf16(a1, qf[1][kc], sT[1][1], 0, 0, 0);
        }

        // softmax (no-max, split-sum) + in-register P A-frag assembly
        bf16x8 pa[2];
        #pragma unroll
        for (int qt = 0; qt < 2; qt++) {
            union { bf16x8 v; u16 s[8]; } pk;
            float ls = 0.f;
            #pragma unroll
            for (int kt = 0; kt < 2; kt++)
                #pragma unroll
                for (int r = 0; r < 4; r++) {
                    float p = __expf(sT[kt][qt][r] * scale);
                    ls += p;
                    pk.s[kt * 4 + r] = f2bf(p);
                }
            lsum[qt] += ls;
            pa[qt] = pk.v;
        }

        // PV (V reads apply the slot swizzle)
        #pragma unroll
        for (int dt = 0; dt < 16; dt++) {
            int row = dt * 16 + l15;
            bf16x8 vf = *(const bf16x8*)(VsC + row * 32 + (quad ^ (row & 3)) * 8);
            o[0][dt] = __builtin_amdgcn_mfma_f32_16x16x32_bf16(pa[0], vf, o[0][dt], 0, 0, 0);
            o[1][dt] = __builtin_amdgcn_mfma_f32_16x16x32_bf16(pa[1], vf, o[1][dt], 0, 0, 0);
        }

        __syncthreads();   // single barrier/iter: drains own DMA + orders buf reads
    }

    size_t rowb = (size_t)bl * NPIX + q0 + w * 32;
    u16* op = Opart + (size_t)split * NE;
    #pragma unroll
    for (int qt = 0; qt < 2; qt++) {
        float v = lsum[qt];
        v += __shfl_xor(v, 16); v += __shfl_xor(v, 32);
        if (quad == 0)
            lpart[(size_t)split * NR + rowb + qt * 16 + l15] = v;
        #pragma unroll
        for (int dt = 0; dt < 16; dt++)
            #pragma unroll
            for (int r = 0; r < 4; r++)
                op[(rowb + qt * 16 + quad * 4 + r) * CH + dt * 16 + l15] = f2bf(o[qt][dt][r]);
    }
}

// ---------- K5: proj GEMM + split-combine + residual ----------
// Epilogue LDS-transpose (alias Ws as 64x132 f32) -> coalesced float4/uint4
// residual loads + stores.
__global__ __launch_bounds__(256, 4) void proj_mfma(const u16* __restrict__ Opart,
                                                    const float* __restrict__ lpart,
                                                    const u16* __restrict__ wp,
                                                    const void* __restrict__ proj_b,
                                                    const void* __restrict__ x,
                                                    void* __restrict__ out,
                                                    int b0, int NE, int NR) {
    __shared__ u16 Ws[64 * WSTR];    // 33 KB
    bool f32 = detect_f32(x);
    int bl = blockIdx.z, bg = b0 + bl;
    int n0 = blockIdx.x * 128, o0 = blockIdx.y * 64;
    int t = threadIdx.x;
    int w = t >> 6, lane = t & 63;
    int l15 = lane & 15, quad = lane >> 4;
    int pbase = n0 + w * 32;

    #pragma unroll
    for (int i = 0; i < 8; i++) {
        int e = t + i * 256;
        *(uint4*)(Ws + (e >> 5) * WSTR + (e & 31) * 8) =
            *(const uint4*)(wp + (size_t)(o0 + (e >> 5)) * CH + (e & 31) * 8);
    }
    __syncthreads();

    // per-lane 1/l for the 2 m-tile rows this lane supplies (A m-index = l15)
    size_t rowg[2]; float invl[2];
    #pragma unroll
    for (int m = 0; m < 2; m++) {
        rowg[m] = (size_t)bl * NPIX + pbase + m * 16 + l15;
        float l = 0.f;
        #pragma unroll
        for (int s = 0; s < NSPLIT; s++) l += lpart[(size_t)s * NR + rowg[m]];
        invl[m] = 1.0f / l;
    }

    f32x4 acc[2][4];
    #pragma unroll
    for (int m = 0; m < 2; m++)
        #pragma unroll
        for (int n = 0; n < 4; n++)
            #pragma unroll
            for (int r = 0; r < 4; r++) acc[m][n][r] = 0.f;

    #pragma unroll
    for (int kc = 0; kc < 8; kc++) {
        bf16x8 afr[2];
        #pragma unroll
        for (int m = 0; m < 2; m++) {
            float f[8] = {0.f,0.f,0.f,0.f,0.f,0.f,0.f,0.f};
            #pragma unroll
            for (int s = 0; s < NSPLIT; s++) {
                bf16x8 v = *(const bf16x8*)(Opart + (size_t)s * NE + rowg[m] * CH + kc * 32 + quad * 8);
                #pragma unroll
                for (int j = 0; j < 8; j++) f[j] += bf2f((u16)v[j]);
            }
            bf16x8 a;
            #pragma unroll
            for (int j = 0; j < 8; j++) a[j] = (short)f2bf(f[j] * invl[m]);
            afr[m] = a;
        }
        #pragma unroll
        for (int n = 0; n < 4; n++) {
            bf16x8 b = *(const bf16x8*)(Ws + (n * 16 + l15) * WSTR + kc * 32 + quad * 8);
            acc[0][n] = __builtin_amdgcn_mfma_f32_16x16x32_bf16(afr[0], b, acc[0][n], 0, 0, 0);
            acc[1][n] = __builtin_amdgcn_mfma_f32_16x16x32_bf16(afr[1], b, acc[1][n], 0, 0, 0);
        }
    }

    // ---- epilogue: transpose via LDS (alias Ws as 64 x 132 f32) ----
    __syncthreads();                     // all waves done reading Ws
    float4* T4 = (float4*)Ws;            // row stride 33 float4 (132 f32, 528B, 16B-aligned)
    #pragma unroll
    for (int n = 0; n < 4; n++) {
        int o = o0 + n * 16 + l15;
        float bias = load1(proj_b, o, f32);
        #pragma unroll
        for (int m = 0; m < 2; m++) {
            float4 v;
            v.x = acc[m][n][0] + bias; v.y = acc[m][n][1] + bias;
            v.z = acc[m][n][2] + bias; v.w = acc[m][n][3] + bias;
            T4[(n * 16 + l15) * 33 + w * 8 + m * 4 + quad] = v;
        }
    }
    __syncthreads();
    const float* Tf = (const float*)Ws;
    if (f32) {
        #pragma unroll
        for (int i = 0; i < 8; i++) {
            int idx = t + i * 256;       // 2048 float4 = 64 rows x 32 cols
            int row = idx >> 5, c4 = idx & 31;
            float4 v = T4[row * 33 + c4];
            size_t go = ((size_t)(bg * CH + o0 + row)) * NPIX + n0 + c4 * 4;
            float4 xr = *(const float4*)((const float*)x + go);
            v.x += xr.x; v.y += xr.y; v.z += xr.z; v.w += xr.w;
            *(float4*)((float*)out + go) = v;
        }
    } else {
        #pragma unroll
        for (int i = 0; i < 4; i++) {
            int idx = t + i * 256;       // 1024 uint4 = 64 rows x 16 cols (8 bf16 each)
            int row = idx >> 4, c8 = idx & 15;
            size_t go = ((size_t)(bg * CH + o0 + row)) * NPIX + n0 + c8 * 8;
            uint4 xr = *(const uint4*)((const u16*)x + go);
            float xf[8]; unpack8(xr, xf);
            union { uint4 v; u16 s[8]; } pk;
            #pragma unroll
            for (int j = 0; j < 8; j++)
                pk.s[j] = f2bf(Tf[row * 132 + c8 * 8 + j] + xf[j]);
            *(uint4*)((u16*)out + go) = pk.v;
        }
    }
}

extern "C" void kernel_launch(void* const* d_in, const int* in_sizes, int n_in,
                              void* d_out, int out_size, void* d_ws, size_t ws_size,
                              hipStream_t stream) {
    const void* x      = d_in[0];
    const void* gn_w   = d_in[1];
    const void* gn_b   = d_in[2];
    const void* qkv_w  = d_in[3];
    const void* qkv_b  = d_in[4];
    const void* proj_w = d_in[5];
    const void* proj_b = d_in[6];

    char* ws = (char*)d_ws;
    float* stats = (float*)ws;                               // 1 KB
    u16* wq = (u16*)(ws + 1024);                             // 384 KB
    u16* wp = wq + 768 * 256;                                // 128 KB
    char* dyn = ws + 1024 + (768 * 256 + 256 * 256) * 2;

    const size_t per_batch = (size_t)NPIX * CH * 2           // xt
                           + (size_t)NPIX * 512 * 2          // qk
                           + (size_t)CH * NPIX * 2           // vt
                           + (size_t)NSPLIT * NPIX * CH * 2  // Opart bf16
                           + (size_t)NSPLIT * NPIX * 4;      // lpart
    const size_t need_full = 1024 + 600 * 1024 + BATCH * per_batch;  // ~66 MB
    int nb = (ws_size >= need_full) ? BATCH : 1;

    u16* xt      = (u16*)dyn;
    u16* qk      = xt + (size_t)nb * NPIX * CH;
    u16* vt      = qk + (size_t)nb * NPIX * 512;
    u16* Opart   = vt + (size_t)nb * CH * NPIX;
    float* lpart = (float*)(Opart + (size_t)NSPLIT * nb * NPIX * CH);
    int NE = nb * NPIX * CH;
    int NR = nb * NPIX;

    wconv<<<dim3(256), 256, 0, stream>>>(qkv_w, proj_w, wq, wp);

    for (int b0 = 0; b0 < BATCH; b0 += nb) {
        gn_stats<<<dim3(nb * NGROUPS), 256, 0, stream>>>(x, stats, b0);
        xgn<<<dim3(NPIX / 64, CH / 64, nb), 256, 0, stream>>>(
            x, gn_w, gn_b, stats, xt, b0);
        qkv_mfma<<<dim3(NPIX / 128 / QTILES, 768 / 64, nb), 256, 0, stream>>>(
            xt, wq, qkv_b, qk, vt);
        attn_mfma<<<dim3(NPIX / 128, NSPLIT, nb), 256, 0, stream>>>(
            qk, vt, Opart, lpart, NE, NR);
        proj_mfma<<<dim3(NPIX / 128, CH / 64, nb), 256, 0, stream>>>(
            Opart, lpart, wp, proj_b, x, d_out, b0, NE, NR);
    }
}

// Round 16
// 208.077 us; speedup vs baseline: 1.0415x; 1.0415x over previous
//
#include <hip/hip_runtime.h>
#include <stdint.h>

typedef unsigned short u16;
typedef __attribute__((ext_vector_type(8))) short bf16x8;   // 8 bf16 = 4 VGPRs
typedef __attribute__((ext_vector_type(4))) float f32x4;

#define BATCH   4
#define CH      256
#define NPIX    4096      // 64*64
#define NGROUPS 32
#define CPG     8
#define EPS     1e-5f

#define NSPLIT 4
#define SPLEN  (NPIX / NSPLIT)
#define ATK    32
#define NIT    (SPLEN / ATK)     // 32
#define WSTR   264        // weight LDS row stride
#define QTILES 2          // qkv: pixel-tiles per block. 2 = verified optimum (R15: 4 cost +8us
                          // via 384-block load imbalance; R11: 1->2 was -4us)

// ---------- bf16 helpers ----------
__device__ __forceinline__ float bf2f(u16 u) {
    union { uint32_t i; float f; } v; v.i = ((uint32_t)u) << 16; return v.f;
}
__device__ __forceinline__ u16 f2bf(float f) {
    union { float f; uint32_t i; } v; v.f = f;
    uint32_t x = v.i;
    uint32_t r = (x + 0x7fffu + ((x >> 16) & 1u)) >> 16;
    return (u16)r;
}
__device__ __forceinline__ void unpack2(uint32_t u, float& a, float& b) {
    union { uint32_t i; float f; } lo, hi;
    lo.i = u << 16; hi.i = u & 0xffff0000u;
    a = lo.f; b = hi.f;
}
__device__ __forceinline__ void unpack8(uint4 u, float* f) {
    unpack2(u.x, f[0], f[1]); unpack2(u.y, f[2], f[3]);
    unpack2(u.z, f[4], f[5]); unpack2(u.w, f[6], f[7]);
}

// ---------- runtime input-dtype detection (fp32 vs bf16 ambiguity) ----------
__device__ __forceinline__ bool detect_f32(const void* xv) {
    const u16* p = (const u16*)xv;
    int bad = 0;
    #pragma unroll
    for (int i = 0; i < 32; i++) {
        u16 v = p[2 * i];
        int e = (v >> 7) & 0xff;
        bad += (e < 0x68 || e > 0x90) ? 1 : 0;
    }
    return bad >= 10;
}
__device__ __forceinline__ float load1(const void* b, size_t i, bool f32) {
    return f32 ? ((const float*)b)[i] : bf2f(((const u16*)b)[i]);
}
__device__ __forceinline__ void store1(void* b, size_t i, bool f32, float v) {
    if (f32) ((float*)b)[i] = v; else ((u16*)b)[i] = f2bf(v);
}
__device__ __forceinline__ void load4v(const void* base, size_t off, bool f32, float* f) {
    if (f32) {
        float4 a = *(const float4*)((const float*)base + off);
        f[0] = a.x; f[1] = a.y; f[2] = a.z; f[3] = a.w;
    } else {
        uint2 u = *(const uint2*)((const u16*)base + off);
        unpack2(u.x, f[0], f[1]); unpack2(u.y, f[2], f[3]);
    }
}
__device__ __forceinline__ void load8v(const void* base, size_t off, bool f32, float* f) {
    if (f32) {
        const float4* p = (const float4*)((const float*)base + off);
        float4 a = p[0], b = p[1];
        f[0] = a.x; f[1] = a.y; f[2] = a.z; f[3] = a.w;
        f[4] = b.x; f[5] = b.y; f[6] = b.z; f[7] = b.w;
    } else {
        uint4 u = *(const uint4*)((const u16*)base + off);
        unpack8(u, f);
    }
}

// ---------- K0: weights -> bf16 ----------
__global__ __launch_bounds__(256) void wconv(const void* __restrict__ qkv_w,
                                             const void* __restrict__ proj_w,
                                             u16* __restrict__ wq, u16* __restrict__ wp) {
    bool f32q = detect_f32(qkv_w);
    bool f32p = detect_f32(proj_w);
    int i = blockIdx.x * 256 + threadIdx.x;
    for (int e = i; e < 768 * 256; e += 256 * 256)
        wq[e] = f2bf(load1(qkv_w, e, f32q));
    for (int e = i; e < 256 * 256; e += 256 * 256)
        wp[e] = f2bf(load1(proj_w, e, f32p));
}

// ---------- K1: GroupNorm stats ----------
__global__ __launch_bounds__(256) void gn_stats(const void* __restrict__ x,
                                                float* __restrict__ stats, int b0) {
    bool f32 = detect_f32(x);
    int bg = b0 * NGROUPS + blockIdx.x;
    int t  = threadIdx.x;
    size_t base = (size_t)bg * (CPG * NPIX);
    float s = 0.f, s2 = 0.f;
    for (int i = t * 8; i < CPG * NPIX; i += 256 * 8) {
        float f[8]; load8v(x, base + i, f32, f);
        #pragma unroll
        for (int e = 0; e < 8; e++) { s += f[e]; s2 += f[e] * f[e]; }
    }
    #pragma unroll
    for (int off = 1; off < 64; off <<= 1) {
        s  += __shfl_xor(s,  off);
        s2 += __shfl_xor(s2, off);
    }
    __shared__ float red[8];
    int w = t >> 6;
    if ((t & 63) == 0) { red[w * 2] = s; red[w * 2 + 1] = s2; }
    __syncthreads();
    if (t == 0) {
        float S  = red[0] + red[2] + red[4] + red[6];
        float S2 = red[1] + red[3] + red[5] + red[7];
        float n  = (float)(CPG * NPIX);
        float mu = S / n;
        float var = S2 / n - mu * mu;
        stats[bg * 2]     = mu;
        stats[bg * 2 + 1] = rsqrtf(var + EPS);
    }
}

// ---------- K2: GN-apply + transpose: x[c][n] -> xt[n][c] normalized bf16 ----------
__global__ __launch_bounds__(256) void xgn(const void* __restrict__ x,
                                           const void* __restrict__ gn_w,
                                           const void* __restrict__ gn_b,
                                           const float* __restrict__ stats,
                                           u16* __restrict__ xt, int b0) {
    bool f32 = detect_f32(x);
    __shared__ u16 T[64][72];
    int bl = blockIdx.z, bg = b0 + bl;
    int n0 = blockIdx.x * 64, c0 = blockIdx.y * 64;
    int t = threadIdx.x;
    int tc = t >> 4, tn = (t & 15) * 4;
    #pragma unroll
    for (int i = 0; i < 4; i++) {
        int cl = tc + i * 16;
        int c = c0 + cl;
        int g = c >> 3;
        float mu = stats[(bg * NGROUPS + g) * 2];
        float rs = stats[(bg * NGROUPS + g) * 2 + 1];
        float wv = load1(gn_w, c, f32) * rs;
        float bv = load1(gn_b, c, f32) - mu * wv;
        float a[4];
        load4v(x, ((size_t)(bg * CH + c)) * NPIX + n0 + tn, f32, a);
        #pragma unroll
        for (int j = 0; j < 4; j++) T[cl][tn + j] = f2bf(a[j] * wv + bv);
    }
    __syncthreads();
    #pragma unroll
    for (int i = 0; i < 2; i++) {
        int e = t + i * 256;
        int nl = e >> 3, cc = (e & 7) * 8;
        union { uint4 v; u16 s[8]; } pk;
        #pragma unroll
        for (int j = 0; j < 8; j++) pk.s[j] = T[cc + j][nl];
        *(uint4*)(xt + ((size_t)(bl * NPIX) + n0 + nl) * CH + c0 + cc) = pk.v;
    }
}

// ---------- K3: QKV GEMM (MFMA; weights in LDS, A direct-global contiguous) ----------
// V stored kv-permuted within 32-groups for the SWAPPED-QK attention:
//   phys kv j -> slot jj = ((j&12)<<1) | ((j>>4)<<2) | (j&3)
// QTILES=2 pixel-tiles per block amortize the 33KB weight stage 2x.
__global__ __launch_bounds__(256, 3) void qkv_mfma(const u16* __restrict__ xt,
                                                   const u16* __restrict__ wq,
                                                   const void* __restrict__ qkv_b,
                                                   u16* __restrict__ qk,
                                                   u16* __restrict__ vt) {
    __shared__ u16 Ws[64 * WSTR];    // 33 KB
    __shared__ u16 T2b[128 * 72];    // 18 KB transpose scratch
    bool f32b = detect_f32(qkv_b);
    int bl = blockIdx.z;
    int o0 = blockIdx.y * 64;
    int t = threadIdx.x;
    int w = t >> 6, lane = t & 63;
    int l15 = lane & 15, quad = lane >> 4;

    #pragma unroll
    for (int i = 0; i < 8; i++) {
        int e = t + i * 256;
        *(uint4*)(Ws + (e >> 5) * WSTR + (e & 31) * 8) =
            *(const uint4*)(wq + (size_t)(o0 + (e >> 5)) * CH + (e & 31) * 8);
    }
    __syncthreads();

    bool isv = (o0 >= 512);
    for (int tt = 0; tt < QTILES; tt++) {
        int n0 = (blockIdx.x * QTILES + tt) * 128;
        int pbase = n0 + w * 32;
        const u16* xa = xt + ((size_t)(bl * NPIX + pbase)) * CH;

        f32x4 acc[2][4];
        #pragma unroll
        for (int m = 0; m < 2; m++)
            #pragma unroll
            for (int n = 0; n < 4; n++)
                #pragma unroll
                for (int r = 0; r < 4; r++) acc[m][n][r] = 0.f;

        #pragma unroll
        for (int kc = 0; kc < 8; kc++) {
            bf16x8 a0 = *(const bf16x8*)(xa + (size_t)(l15) * CH + kc * 32 + quad * 8);
            bf16x8 a1 = *(const bf16x8*)(xa + (size_t)(16 + l15) * CH + kc * 32 + quad * 8);
            #pragma unroll
            for (int n = 0; n < 4; n++) {
                bf16x8 b = *(const bf16x8*)(Ws + (n * 16 + l15) * WSTR + kc * 32 + quad * 8);
                acc[0][n] = __builtin_amdgcn_mfma_f32_16x16x32_bf16(a0, b, acc[0][n], 0, 0, 0);
                acc[1][n] = __builtin_amdgcn_mfma_f32_16x16x32_bf16(a1, b, acc[1][n], 0, 0, 0);
            }
        }

        if (!isv) {
            // ---- q/k: LDS transpose (T2b) + coalesced uint4 stores ----
            __syncthreads();          // prior tile's T2b reads complete
            #pragma unroll
            for (int n = 0; n < 4; n++) {
                int o = o0 + n * 16 + l15;
                float bias = load1(qkv_b, o, f32b);
                #pragma unroll
                for (int m = 0; m < 2; m++)
                    #pragma unroll
                    for (int r = 0; r < 4; r++) {
                        int prow = w * 32 + m * 16 + quad * 4 + r;
                        T2b[prow * 72 + n * 16 + l15] = f2bf(acc[m][n][r] + bias);
                    }
            }
            __syncthreads();
            #pragma unroll
            for (int i = 0; i < 4; i++) {
                int e = t + i * 256;  // 1024 entries = 128 pix x 8 chunks
                int p = e >> 3, c = (e & 7) * 8;
                uint4 v = *(const uint4*)(T2b + p * 72 + c);
                *(uint4*)(qk + ((size_t)(bl * NPIX + n0 + p)) * 512 + o0 + c) = v;
            }
        } else {
            // ---- v: packed uint2 stores (4 contiguous u16 per (n,m)) ----
            #pragma unroll
            for (int n = 0; n < 4; n++) {
                int o = o0 + n * 16 + l15;
                float bias = load1(qkv_b, o, f32b);
                size_t rowb = ((size_t)(bl * CH + o - 512)) * NPIX + pbase;
                #pragma unroll
                for (int m = 0; m < 2; m++) {
                    union { uint2 v; u16 s[4]; } pk;
                    #pragma unroll
                    for (int r = 0; r < 4; r++) pk.s[r] = f2bf(acc[m][n][r] + bias);
                    *(uint2*)(vt + rowb + quad * 8 + m * 4) = pk.v;
                }
            }
        }
    }
}

// ---------- K4: MFMA flash attention — byte-exact R12 (verified best, ~87us) ----------
// attn is latency-pinned: 6 schedule variants all land 87-90us; registers exactly
// full (4 spill confirmations); direct-global operands fatal (2 confirmations).
__global__ __launch_bounds__(256, 2) void attn_mfma(const u16* __restrict__ qk,
                                                    const u16* __restrict__ vt,
                                                    u16* __restrict__ Opart,
                                                    float* __restrict__ lpart,
                                                    int NE, int NR) {
    __shared__ u16 Ks[2][ATK * 256];     // 2 x 16 KB, col-swizzled (col ^ (row&7))
    __shared__ u16 Vts[2][CH * 32];      // 2 x 16 KB, slot-swizzled (slot ^ (row&3))
    int bl    = blockIdx.z;
    int split = blockIdx.y;
    int q0    = blockIdx.x * 128;
    int t     = threadIdx.x;
    int w     = t >> 6, lane = t & 63;
    int l15   = lane & 15, quad = lane >> 4;

    const u16* qkb = qk + (size_t)bl * NPIX * 512;
    const u16* vtb = vt + (size_t)bl * CH * NPIX;
    int kvbase = split * SPLEN;

    // Q fragments (B-operand of swapped QK): lane l15 = q-col, k = quad*8+e
    bf16x8 qf[2][8];
    #pragma unroll
    for (int m = 0; m < 2; m++) {
        const u16* qrow = qkb + (size_t)(q0 + w * 32 + m * 16 + l15) * 512;
        #pragma unroll
        for (int kc = 0; kc < 8; kc++)
            qf[m][kc] = *(const bf16x8*)(qrow + kc * 32 + quad * 8);
    }
    f32x4 o[2][16];
    #pragma unroll
    for (int m = 0; m < 2; m++)
        #pragma unroll
        for (int i = 0; i < 16; i++)
            #pragma unroll
            for (int r = 0; r < 4; r++) o[m][i][r] = 0.f;
    float lsum[2] = {0.f, 0.f};
    const float scale = 0.0625f;
    int swz = l15 & 7;

    // ---- prologue: DMA tile 0 into buffer 0, drain ----
    #pragma unroll
    for (int i = 0; i < 4; i++) {
        int g = t + i * 256;
        int row = g >> 5, pcol = g & 31;
        int lcol = pcol ^ (row & 7);
        __builtin_amdgcn_global_load_lds(
            (const void*)(qkb + (size_t)(kvbase + row) * 512 + 256 + lcol * 8),
            (void*)(&Ks[0][0] + (size_t)g * 8), 16, 0, 0);
    }
    #pragma unroll
    for (int i = 0; i < 4; i++) {
        int g = t + i * 256;
        int row = g >> 2, s = g & 3;
        __builtin_amdgcn_global_load_lds(
            (const void*)(vtb + (size_t)row * NPIX + kvbase + (s ^ (row & 3)) * 8),
            (void*)(&Vts[0][0] + (size_t)g * 8), 16, 0, 0);
    }
    __syncthreads();

    for (int it = 0; it < NIT; it++) {
        int cur = it & 1;
        // issue tile t+1's DMA into the other buffer — latency hides under compute
        if (it + 1 < NIT) {
            int kv1 = kvbase + (it + 1) * ATK;
            u16* KsB = &Ks[cur ^ 1][0];
            u16* VsB = &Vts[cur ^ 1][0];
            #pragma unroll
            for (int i = 0; i < 4; i++) {
                int g = t + i * 256;
                int row = g >> 5, pcol = g & 31;
                int lcol = pcol ^ (row & 7);
                __builtin_amdgcn_global_load_lds(
                    (const void*)(qkb + (size_t)(kv1 + row) * 512 + 256 + lcol * 8),
                    (void*)(KsB + (size_t)g * 8), 16, 0, 0);
            }
            #pragma unroll
            for (int i = 0; i < 4; i++) {
                int g = t + i * 256;
                int row = g >> 2, s = g & 3;
                __builtin_amdgcn_global_load_lds(
                    (const void*)(vtb + (size_t)row * NPIX + kv1 + (s ^ (row & 3)) * 8),
                    (void*)(VsB + (size_t)g * 8), 16, 0, 0);
            }
        }
        const u16* KsC = &Ks[cur][0];
        const u16* VsC = &Vts[cur][0];

        // S^T = K.Q^T (K reads use the same XOR swizzle as the DMA source)
        f32x4 sT[2][2];
        #pragma unroll
        for (int kt = 0; kt < 2; kt++)
            #pragma unroll
            for (int qt = 0; qt < 2; qt++)
                #pragma unroll
                for (int r = 0; r < 4; r++) sT[kt][qt][r] = 0.f;
        #pragma unroll
        for (int kc = 0; kc < 8; kc++) {
            int sc = (kc * 4 + quad) ^ swz;
            bf16x8 a0 = *(const bf16x8*)(KsC + l15 * 256 + sc * 8);
            bf16x8 a1 = *(const bf16x8*)(KsC + (16 + l15) * 256 + sc * 8);
            sT[0][0] = __builtin_amdgcn_mfma_f32_16x16x32_bf16(a0, qf[0][kc], sT[0][0], 0, 0, 0);
            sT[0][1] = __builtin_amdgcn_mfma_f32_16x16x32_bf16(a0, qf[1][kc], sT[0][1], 0, 0, 0);
            sT[1][0] = __builtin_amdgcn_mfma_f32_16x16x32_bf16(a1, qf[0][kc], sT[1][0], 0, 0, 0);
            sT[1][1] = __builtin_amdgcn_mfma_f32_16x16x32_bf16(a1, qf[1][kc], sT[1][1], 0, 0, 0);
        }

        // softmax (no-max, split-sum) + in-register P A-frag assembly
        bf16x8 pa[2];
        #pragma unroll
        for (int qt = 0; qt < 2; qt++) {
            union { bf16x8 v; u16 s[8]; } pk;
            float ls = 0.f;
            #pragma unroll
            for (int kt = 0; kt < 2; kt++)
                #pragma unroll
                for (int r = 0; r < 4; r++) {
                    float p = __expf(sT[kt][qt][r] * scale);
                    ls += p;
                    pk.s[kt * 4 + r] = f2bf(p);
                }
            lsum[qt] += ls;
            pa[qt] = pk.v;
        }

        // PV (V reads apply the slot swizzle)
        #pragma unroll
        for (int dt = 0; dt < 16; dt++) {
            int row = dt * 16 + l15;
            bf16x8 vf = *(const bf16x8*)(VsC + row * 32 + (quad ^ (row & 3)) * 8);
            o[0][dt] = __builtin_amdgcn_mfma_f32_16x16x32_bf16(pa[0], vf, o[0][dt], 0, 0, 0);
            o[1][dt] = __builtin_amdgcn_mfma_f32_16x16x32_bf16(pa[1], vf, o[1][dt], 0, 0, 0);
        }

        __syncthreads();   // single barrier/iter: drains own DMA + orders buf reads
    }

    size_t rowb = (size_t)bl * NPIX + q0 + w * 32;
    u16* op = Opart + (size_t)split * NE;
    #pragma unroll
    for (int qt = 0; qt < 2; qt++) {
        float v = lsum[qt];
        v += __shfl_xor(v, 16); v += __shfl_xor(v, 32);
        if (quad == 0)
            lpart[(size_t)split * NR + rowb + qt * 16 + l15] = v;
        #pragma unroll
        for (int dt = 0; dt < 16; dt++)
            #pragma unroll
            for (int r = 0; r < 4; r++)
                op[(rowb + qt * 16 + quad * 4 + r) * CH + dt * 16 + l15] = f2bf(o[qt][dt][r]);
    }
}

// ---------- K5: proj GEMM + split-combine + residual ----------
// Epilogue LDS-transpose (alias Ws as 64x132 f32) -> coalesced float4/uint4
// residual loads + stores.
__global__ __launch_bounds__(256, 4) void proj_mfma(const u16* __restrict__ Opart,
                                                    const float* __restrict__ lpart,
                                                    const u16* __restrict__ wp,
                                                    const void* __restrict__ proj_b,
                                                    const void* __restrict__ x,
                                                    void* __restrict__ out,
                                                    int b0, int NE, int NR) {
    __shared__ u16 Ws[64 * WSTR];    // 33 KB
    bool f32 = detect_f32(x);
    int bl = blockIdx.z, bg = b0 + bl;
    int n0 = blockIdx.x * 128, o0 = blockIdx.y * 64;
    int t = threadIdx.x;
    int w = t >> 6, lane = t & 63;
    int l15 = lane & 15, quad = lane >> 4;
    int pbase = n0 + w * 32;

    #pragma unroll
    for (int i = 0; i < 8; i++) {
        int e = t + i * 256;
        *(uint4*)(Ws + (e >> 5) * WSTR + (e & 31) * 8) =
            *(const uint4*)(wp + (size_t)(o0 + (e >> 5)) * CH + (e & 31) * 8);
    }
    __syncthreads();

    // per-lane 1/l for the 2 m-tile rows this lane supplies (A m-index = l15)
    size_t rowg[2]; float invl[2];
    #pragma unroll
    for (int m = 0; m < 2; m++) {
        rowg[m] = (size_t)bl * NPIX + pbase + m * 16 + l15;
        float l = 0.f;
        #pragma unroll
        for (int s = 0; s < NSPLIT; s++) l += lpart[(size_t)s * NR + rowg[m]];
        invl[m] = 1.0f / l;
    }

    f32x4 acc[2][4];
    #pragma unroll
    for (int m = 0; m < 2; m++)
        #pragma unroll
        for (int n = 0; n < 4; n++)
            #pragma unroll
            for (int r = 0; r < 4; r++) acc[m][n][r] = 0.f;

    #pragma unroll
    for (int kc = 0; kc < 8; kc++) {
        bf16x8 afr[2];
        #pragma unroll
        for (int m = 0; m < 2; m++) {
            float f[8] = {0.f,0.f,0.f,0.f,0.f,0.f,0.f,0.f};
            #pragma unroll
            for (int s = 0; s < NSPLIT; s++) {
                bf16x8 v = *(const bf16x8*)(Opart + (size_t)s * NE + rowg[m] * CH + kc * 32 + quad * 8);
                #pragma unroll
                for (int j = 0; j < 8; j++) f[j] += bf2f((u16)v[j]);
            }
            bf16x8 a;
            #pragma unroll
            for (int j = 0; j < 8; j++) a[j] = (short)f2bf(f[j] * invl[m]);
            afr[m] = a;
        }
        #pragma unroll
        for (int n = 0; n < 4; n++) {
            bf16x8 b = *(const bf16x8*)(Ws + (n * 16 + l15) * WSTR + kc * 32 + quad * 8);
            acc[0][n] = __builtin_amdgcn_mfma_f32_16x16x32_bf16(afr[0], b, acc[0][n], 0, 0, 0);
            acc[1][n] = __builtin_amdgcn_mfma_f32_16x16x32_bf16(afr[1], b, acc[1][n], 0, 0, 0);
        }
    }

    // ---- epilogue: transpose via LDS (alias Ws as 64 x 132 f32) ----
    __syncthreads();                     // all waves done reading Ws
    float4* T4 = (float4*)Ws;            // row stride 33 float4 (132 f32, 528B, 16B-aligned)
    #pragma unroll
    for (int n = 0; n < 4; n++) {
        int o = o0 + n * 16 + l15;
        float bias = load1(proj_b, o, f32);
        #pragma unroll
        for (int m = 0; m < 2; m++) {
            float4 v;
            v.x = acc[m][n][0] + bias; v.y = acc[m][n][1] + bias;
            v.z = acc[m][n][2] + bias; v.w = acc[m][n][3] + bias;
            T4[(n * 16 + l15) * 33 + w * 8 + m * 4 + quad] = v;
        }
    }
    __syncthreads();
    const float* Tf = (const float*)Ws;
    if (f32) {
        #pragma unroll
        for (int i = 0; i < 8; i++) {
            int idx = t + i * 256;       // 2048 float4 = 64 rows x 32 cols
            int row = idx >> 5, c4 = idx & 31;
            float4 v = T4[row * 33 + c4];
            size_t go = ((size_t)(bg * CH + o0 + row)) * NPIX + n0 + c4 * 4;
            float4 xr = *(const float4*)((const float*)x + go);
            v.x += xr.x; v.y += xr.y; v.z += xr.z; v.w += xr.w;
            *(float4*)((float*)out + go) = v;
        }
    } else {
        #pragma unroll
        for (int i = 0; i < 4; i++) {
            int idx = t + i * 256;       // 1024 uint4 = 64 rows x 16 cols (8 bf16 each)
            int row = idx >> 4, c8 = idx & 15;
            size_t go = ((size_t)(bg * CH + o0 + row)) * NPIX + n0 + c8 * 8;
            uint4 xr = *(const uint4*)((const u16*)x + go);
            float xf[8]; unpack8(xr, xf);
            union { uint4 v; u16 s[8]; } pk;
            #pragma unroll
            for (int j = 0; j < 8; j++)
                pk.s[j] = f2bf(Tf[row * 132 + c8 * 8 + j] + xf[j]);
            *(uint4*)((u16*)out + go) = pk.v;
        }
    }
}

extern "C" void kernel_launch(void* const* d_in, const int* in_sizes, int n_in,
                              void* d_out, int out_size, void* d_ws, size_t ws_size,
                              hipStream_t stream) {
    const void* x      = d_in[0];
    const void* gn_w   = d_in[1];
    const void* gn_b   = d_in[2];
    const void* qkv_w  = d_in[3];
    const void* qkv_b  = d_in[4];
    const void* proj_w = d_in[5];
    const void* proj_b = d_in[6];

    char* ws = (char*)d_ws;
    float* stats = (float*)ws;                               // 1 KB
    u16* wq = (u16*)(ws + 1024);                             // 384 KB
    u16* wp = wq + 768 * 256;                                // 128 KB
    char* dyn = ws + 1024 + (768 * 256 + 256 * 256) * 2;

    const size_t per_batch = (size_t)NPIX * CH * 2           // xt
                           + (size_t)NPIX * 512 * 2          // qk
                           + (size_t)CH * NPIX * 2           // vt
                           + (size_t)NSPLIT * NPIX * CH * 2  // Opart bf16
                           + (size_t)NSPLIT * NPIX * 4;      // lpart
    const size_t need_full = 1024 + 600 * 1024 + BATCH * per_batch;  // ~66 MB
    int nb = (ws_size >= need_full) ? BATCH : 1;

    u16* xt      = (u16*)dyn;
    u16* qk      = xt + (size_t)nb * NPIX * CH;
    u16* vt      = qk + (size_t)nb * NPIX * 512;
    u16* Opart   = vt + (size_t)nb * CH * NPIX;
    float* lpart = (float*)(Opart + (size_t)NSPLIT * nb * NPIX * CH);
    int NE = nb * NPIX * CH;
    int NR = nb * NPIX;

    wconv<<<dim3(256), 256, 0, stream>>>(qkv_w, proj_w, wq, wp);

    for (int b0 = 0; b0 < BATCH; b0 += nb) {
        gn_stats<<<dim3(nb * NGROUPS), 256, 0, stream>>>(x, stats, b0);
        xgn<<<dim3(NPIX / 64, CH / 64, nb), 256, 0, stream>>>(
            x, gn_w, gn_b, stats, xt, b0);
        qkv_mfma<<<dim3(NPIX / 128 / QTILES, 768 / 64, nb), 256, 0, stream>>>(
            xt, wq, qkv_b, qk, vt);
        attn_mfma<<<dim3(NPIX / 128, NSPLIT, nb), 256, 0, stream>>>(
            qk, vt, Opart, lpart, NE, NR);
        proj_mfma<<<dim3(NPIX / 128, CH / 64, nb), 256, 0, stream>>>(
            Opart, lpart, wp, proj_b, x, d_out, b0, NE, NR);
    }
}